// Round 9
// baseline (438.744 us; speedup 1.0000x reference)
//
#include <hip/hip_runtime.h>
#include <math.h>

#define NN 512
#define BB 128
#define CIN 66
#define QQ (BB*CIN)            // 8448
#define AN ((size_t)NN*NN)
#define HB 480                 // feature rows per batch: 462 used (7 segs x 66)
#define KTOT 480               // padded K for proj (Wt rows 462..479 are zero)

typedef unsigned short ushort_t;
typedef __attribute__((ext_vector_type(8))) short short8;
typedef __attribute__((ext_vector_type(8))) unsigned short us8;
typedef __attribute__((ext_vector_type(4))) float f32x4;
typedef __attribute__((ext_vector_type(4))) unsigned short us4;

// Fragment-packed X layout ("Xpack"): element (b, frow, n) lives at
//   ((b*30 + frow/16) << 13) + ((n/8) << 7) + ((frow%16) << 3) + (n%8)
__device__ __forceinline__ size_t pidx(int b, int frow, int n) {
    return ((size_t)(b * 30 + (frow >> 4)) << 13) + ((size_t)(n >> 3) << 7)
         + ((frow & 15) << 3) + (n & 7);
}

__device__ __forceinline__ ushort_t f2bf(float f) {
    unsigned u = __float_as_uint(f);
    u += 0x7FFF + ((u >> 16) & 1);
    return (ushort_t)(u >> 16);
}
__device__ __forceinline__ float bf2f(ushort_t h) {
    return __uint_as_float(((unsigned)h) << 16);
}
__device__ __forceinline__ void split_bf(float f, ushort_t& hi, ushort_t& lo) {
    hi = f2bf(f);
    lo = f2bf(f - bf2f(hi));
}
__device__ __forceinline__ void gload_lds16(const void* g, void* l) {
    __builtin_amdgcn_global_load_lds(
        (const __attribute__((address_space(1))) unsigned*)g,
        (__attribute__((address_space(3))) unsigned*)l, 16, 0, 0);
}

// ---------- adp pair: z selects (nv1_1,nv2_1)->ADP1 or (nv1_2,nv2_2)->ADP2 ----------
__global__ __launch_bounds__(512) void adp_pair_kernel(const float* __restrict__ nv1a,
                                                       const float* __restrict__ nv2a,
                                                       const float* __restrict__ nv1b,
                                                       const float* __restrict__ nv2b,
                                                       float* __restrict__ adp1,
                                                       float* __restrict__ adp2) {
    const float* nv1 = blockIdx.z ? nv1b : nv1a;
    const float* nv2 = blockIdx.z ? nv2b : nv2a;
    float* adp       = blockIdx.z ? adp2 : adp1;
    int n = blockIdx.x;
    int m = threadIdx.x;
    float z = 0.f;
#pragma unroll
    for (int k = 0; k < 10; k++) z = fmaf(nv1[n * 10 + k], nv2[k * NN + m], z);
    z = fmaxf(z, 0.f);

    __shared__ float sred[8];
    int wid  = threadIdx.x >> 6;
    int lane = threadIdx.x & 63;

    float v = z;
#pragma unroll
    for (int off = 32; off; off >>= 1) v = fmaxf(v, __shfl_down(v, off, 64));
    if (lane == 0) sred[wid] = v;
    __syncthreads();
    float zmax = sred[0];
#pragma unroll
    for (int i = 1; i < 8; i++) zmax = fmaxf(zmax, sred[i]);

    float e = __expf(z - zmax);
    __syncthreads();
    v = e;
#pragma unroll
    for (int off = 32; off; off >>= 1) v += __shfl_down(v, off, 64);
    if (lane == 0) sred[wid] = v;
    __syncthreads();
    float tot = 0.f;
#pragma unroll
    for (int i = 0; i < 8; i++) tot += sred[i];

    adp[n * NN + m] = e / tot;
}

// ---------- transpose + bf16-split supports into MFMA-fragment-packed layout ----------
__global__ __launch_bounds__(256) void asplit_kernel(const float* __restrict__ A0,
                                                     const float* __restrict__ A1,
                                                     const float* __restrict__ P1,
                                                     const float* __restrict__ P2,
                                                     ushort_t* __restrict__ Ahi,
                                                     ushort_t* __restrict__ Alo) {
    __shared__ float t[32][33];
    int s = blockIdx.z;
    const float* src = (s == 0) ? A0 : (s == 1) ? A1 : (s == 2) ? P1 : P2;
    int m0 = blockIdx.x * 32, k0 = blockIdx.y * 32;
    int tx = threadIdx.x & 31, ty = threadIdx.x >> 5;
#pragma unroll
    for (int r = 0; r < 32; r += 8)
        t[ty + r][tx] = src[(size_t)(k0 + ty + r) * NN + m0 + tx];
    __syncthreads();
#pragma unroll
    for (int r = 0; r < 32; r += 8) {
        int m = m0 + ty + r, k = k0 + tx;
        float v = t[tx][ty + r];   // = src[k][m]
        ushort_t h, l; split_bf(v, h, l);
        int mt = m >> 4, l15 = m & 15;
        int kt = k >> 5, quad = (k >> 3) & 3, j = k & 7;
        size_t o = ((((size_t)s * 16 + kt) * 32 + mt) * 64 + quad * 16 + l15) * 8 + j;
        Ahi[o] = h; Alo[o] = l;
    }
}

// ---------- fused misc prep: wtprep(W1) + wtprep(W2) + buildx, by block range ----------
__global__ __launch_bounds__(256) void prep_misc_kernel(const float* __restrict__ W1,
                                                        const float* __restrict__ W2,
                                                        const float* __restrict__ inp,
                                                        const float* __restrict__ st,
                                                        ushort_t* __restrict__ Wt1h,
                                                        ushort_t* __restrict__ Wt1l,
                                                        ushort_t* __restrict__ Wt2h,
                                                        ushort_t* __restrict__ Wt2l,
                                                        ushort_t* __restrict__ Xh,
                                                        ushort_t* __restrict__ Xl) {
    int blk = blockIdx.x;
    if (blk < 128) {                       // Wt1[j][KTOT]
        int j = blk;
        for (int k = threadIdx.x; k < KTOT; k += 256) {
            float v = (k < 462) ? W1[(size_t)k * 128 + j] : 0.f;
            ushort_t h, l; split_bf(v, h, l);
            Wt1h[(size_t)j * KTOT + k] = h;
            Wt1l[(size_t)j * KTOT + k] = l;
        }
    } else if (blk < 192) {                // Wt2[j][KTOT]
        int j = blk - 128;
        for (int k = threadIdx.x; k < KTOT; k += 256) {
            float v = (k < 462) ? W2[(size_t)k * 64 + j] : 0.f;
            ushort_t h, l; split_bf(v, h, l);
            Wt2h[(size_t)j * KTOT + k] = h;
            Wt2l[(size_t)j * KTOT + k] = l;
        }
    } else {                               // buildx: Xpack frows 0..65
        int gid = (blk - 192) * 256 + threadIdx.x;   // over 128*66*64
        int ch  = gid & 63;
        int c   = (gid >> 6) % CIN;
        int b   = gid / (64 * CIN);
        int n0  = ch * 8;
        us8 h8, l8;
#pragma unroll
        for (int r = 0; r < 8; r++) {
            int n = n0 + r;
            float v = (c < 2) ? inp[((size_t)b * NN + n) * 2 + c]
                              : st[((size_t)b * NN + n) * 64 + (c - 2)];
            ushort_t h, l; split_bf(v, h, l);
            h8[r] = h; l8[r] = l;
        }
        size_t o = pidx(b, c, n0);
        *(us8*)&Xh[o] = h8;
        *(us8*)&Xl[o] = l8;
    }
}

// ---------- fused 2-hop diffusion GEMM ----------
// Block owns 64-wide q-slab + all 512 nodes. 8 waves of 64m x 64q.
// Phase 1: x1 = A^T x (global frag-packed operands); epilogue writes x1 to
// global Xpack (for proj + phase-2 lo) AND parks x1-hi in LDS (XOR-swizzled).
// Phase 2: x2 = A^T x1, hi-frags from LDS, lo-frags from global (L2-resident).
__global__ __launch_bounds__(512, 4) void diff_fused(const ushort_t* __restrict__ Aph,
                                                     const ushort_t* __restrict__ Apl,
                                                     ushort_t* Xh, ushort_t* Xl, int s2) {
    __shared__ ushort_t sX1h[64 * 512];               // x1-hi, [qloc][chunk-swizzled n]
    const int tid  = threadIdx.x;
    const int lane = tid & 63, w = tid >> 6;          // w 0..7
    const int quad = lane >> 4, l15 = lane & 15;
    const int q0 = blockIdx.x * 64;
    const int sz = blockIdx.z;
    const int sup = (sz < 2) ? sz : s2;
    const size_t abase = (size_t)sup * 262144;        // 16*32*64*8
    const int mtg0 = w * 4;                           // wave m-base = w*64

    int bq[4], cq[4], qloc[4];
#pragma unroll
    for (int qt = 0; qt < 4; qt++) {
        int q = q0 + qt * 16 + l15;
        bq[qt] = q / 66;
        cq[qt] = q - 66 * bq[qt];
        qloc[qt] = qt * 16 + l15;
    }

#define DMFMA4(ACC, AH, AL, XH, XL)                                                                \
    {                                                                                              \
        _Pragma("unroll")                                                                          \
        for (int mt = 0; mt < 4; mt++) {                                                           \
            _Pragma("unroll")                                                                      \
            for (int qt = 0; qt < 4; qt++) {                                                       \
                ACC[mt][qt] = __builtin_amdgcn_mfma_f32_16x16x32_bf16(AH[mt], XH[qt], ACC[mt][qt], 0, 0, 0); \
                ACC[mt][qt] = __builtin_amdgcn_mfma_f32_16x16x32_bf16(AH[mt], XL[qt], ACC[mt][qt], 0, 0, 0); \
                ACC[mt][qt] = __builtin_amdgcn_mfma_f32_16x16x32_bf16(AL[mt], XH[qt], ACC[mt][qt], 0, 0, 0); \
                ACC[mt][qt] = __builtin_amdgcn_mfma_f32_16x16x32_bf16(AL[mt], XL[qt], ACC[mt][qt], 0, 0, 0); \
            }                                                                                      \
        }                                                                                          \
    }

    // ---------------- phase 1: x1 = A^T x (frows 0..65 in, 66+132s out) ----------------
    {
        const ushort_t* xph[4];
        const ushort_t* xpl[4];
#pragma unroll
        for (int qt = 0; qt < 4; qt++) {
            int c = cq[qt];
            size_t off = ((size_t)(bq[qt] * 30 + (c >> 4)) << 13) + ((c & 15) << 3)
                       + (size_t)quad * 128;
            xph[qt] = Xh + off;
            xpl[qt] = Xl + off;
        }
        f32x4 acc[4][4] = {};
        for (int kt = 0; kt < 16; kt++) {
            short8 ah[4], al[4], xh4[4], xl4[4];
#pragma unroll
            for (int t = 0; t < 4; t++) {
                size_t fo = abase + ((size_t)kt * 32 + mtg0 + t) * 512 + lane * 8;
                ah[t] = *(const short8*)&Aph[fo];
                al[t] = *(const short8*)&Apl[fo];
            }
#pragma unroll
            for (int qt = 0; qt < 4; qt++) {
                xh4[qt] = *(const short8*)&xph[qt][(size_t)kt * 512];
                xl4[qt] = *(const short8*)&xpl[qt][(size_t)kt * 512];
            }
            DMFMA4(acc, ah, al, xh4, xl4);
        }
        const int rowo = 66 + 132 * sz;
#pragma unroll
        for (int qt = 0; qt < 4; qt++) {
            int frow = rowo + cq[qt];
#pragma unroll
            for (int mt = 0; mt < 4; mt++) {
                int n = w * 64 + mt * 16 + quad * 4;
                us4 h4, l4;
#pragma unroll
                for (int r = 0; r < 4; r++) {
                    ushort_t h, l; split_bf(acc[mt][qt][r], h, l);
                    h4[r] = h; l4[r] = l;
                }
                size_t o = pidx(bq[qt], frow, n);
                *(us4*)&Xh[o] = h4;
                *(us4*)&Xl[o] = l4;
                // park hi in LDS, XOR-swizzled chunks (2-way max on banks)
                int chunk = (n >> 3) ^ (qloc[qt] & 7);
                *(us4*)&sX1h[qloc[qt] * 512 + chunk * 8 + (quad & 1) * 4] = h4;
            }
        }
    }
    __syncthreads();   // LDS visible + vmcnt(0) drain for x1-lo global stores

    // ---------------- phase 2: x2 = A^T x1 (hi from LDS, lo from global) ----------------
    {
        const int rowi = 66 + 132 * sz;
        const ushort_t* xpl[4];
#pragma unroll
        for (int qt = 0; qt < 4; qt++) {
            int frow = rowi + cq[qt];
            size_t off = ((size_t)(bq[qt] * 30 + (frow >> 4)) << 13) + ((frow & 15) << 3)
                       + (size_t)quad * 128;
            xpl[qt] = Xl + off;
        }
        f32x4 acc[4][4] = {};
        for (int kt = 0; kt < 16; kt++) {
            short8 ah[4], al[4], xh4[4], xl4[4];
#pragma unroll
            for (int t = 0; t < 4; t++) {
                size_t fo = abase + ((size_t)kt * 32 + mtg0 + t) * 512 + lane * 8;
                ah[t] = *(const short8*)&Aph[fo];
                al[t] = *(const short8*)&Apl[fo];
            }
#pragma unroll
            for (int qt = 0; qt < 4; qt++) {
                int chunk = (kt * 4 + quad) ^ (qloc[qt] & 7);
                xh4[qt] = *(const short8*)&sX1h[qloc[qt] * 512 + chunk * 8];
                xl4[qt] = *(const short8*)&xpl[qt][(size_t)kt * 512];
            }
            DMFMA4(acc, ah, al, xh4, xl4);
        }
        const int rowo = 132 + 132 * sz;
#pragma unroll
        for (int qt = 0; qt < 4; qt++) {
            int frow = rowo + cq[qt];
#pragma unroll
            for (int mt = 0; mt < 4; mt++) {
                int n = w * 64 + mt * 16 + quad * 4;
                us4 h4, l4;
#pragma unroll
                for (int r = 0; r < 4; r++) {
                    ushort_t h, l; split_bf(acc[mt][qt][r], h, l);
                    h4[r] = h; l4[r] = l;
                }
                size_t o = pidx(bq[qt], frow, n);
                *(us4*)&Xh[o] = h4;
                *(us4*)&Xl[o] = l4;
            }
        }
    }
#undef DMFMA4
}

// ---------- projection GEMM (MFMA, split-bf16), A transposed in LDS from Xpack ----------
// out[n][j] = sum_f Xpack[b][f][n] * Wt[j][f]   (f = 480, 15 steps of 32)
// LAYER1 (COUT=128, BM=128): sigmoid; j<64 -> r*state into Xpack frows 2+j; j>=64 -> U
// LAYER2 (COUT=64, BM=256): tanh + gate -> out
template <int COUT, int LAYER, int BM>
__global__ __launch_bounds__(256) void proj_mfma(const ushort_t* XhC, const ushort_t* XlC,
                                                 const ushort_t* __restrict__ Wth,
                                                 const ushort_t* __restrict__ Wtl,
                                                 const float* __restrict__ bias,
                                                 const float* __restrict__ state,
                                                 float* U,
                                                 ushort_t* Xhw, ushort_t* Xlw,
                                                 float* __restrict__ out) {
    __shared__ ushort_t sAh[BM * 32];
    __shared__ ushort_t sAl[BM * 32];
    __shared__ ushort_t sBh[COUT * 32];
    __shared__ ushort_t sBl[COUT * 32];
    constexpr int PB = COUT / 64;
    const int tid  = threadIdx.x;
    const int lane = tid & 63, w = tid >> 6;
    const int quad = lane >> 4, l15 = lane & 15;
    const int b = blockIdx.y, n0 = blockIdx.x * BM;
    const int wn = (COUT == 128) ? (w & 1) : w;
    const int wj = (COUT == 128) ? (w >> 1) : 0;
    const int kp = tid & 15, n8 = tid >> 4;

    size_t boff[PB]; int lB[PB];
#pragma unroll
    for (int p = 0; p < PB; p++) {
        int cid = p * 256 + tid;
        lB[p]   = cid * 8;
        boff[p] = (size_t)(cid >> 2) * KTOT + (cid & 3) * 8;
    }

    f32x4 acc[4][4] = {};

    for (int k0 = 0; k0 < KTOT; k0 += 32) {
        __syncthreads();
        // ---- A: load Xpack (f-pairs at 8 consecutive n), write transposed into sAt[n][f] ----
#pragma unroll
        for (int pass = 0; pass < BM / 128; pass++) {
            int np0 = (n8 + pass * 16) * 8;
            int kk  = k0 + 2 * kp;                 // kk&15 even -> kk,kk+1 in same tile
            size_t o = pidx(b, kk, n0 + np0);
            us8 h0 = *(const us8*)&XhC[o];
            us8 h1 = *(const us8*)&XhC[o + 8];
            us8 l0 = *(const us8*)&XlC[o];
            us8 l1 = *(const us8*)&XlC[o + 8];
            int g = kp >> 2, ko = (2 * kp) & 7;
#pragma unroll
            for (int j2 = 0; j2 < 8; j2++) {
                int n   = np0 + j2;
                int idx = n * 32 + ((g ^ ((n >> 1) & 3)) << 3) + ko;
                *(unsigned*)&sAh[idx] = (unsigned)h0[j2] | ((unsigned)h1[j2] << 16);
                *(unsigned*)&sAl[idx] = (unsigned)l0[j2] | ((unsigned)l1[j2] << 16);
            }
        }
        // ---- B: k-contiguous async staging ----
#pragma unroll
        for (int p = 0; p < PB; p++) {
            gload_lds16(Wth + boff[p] + k0, sBh + lB[p]);
            gload_lds16(Wtl + boff[p] + k0, sBl + lB[p]);
        }
        __syncthreads();
        short8 ah[4], al[4], bh[4], bl[4];
#pragma unroll
        for (int t = 0; t < 4; t++) {
            int an  = wn * 64 + t * 16 + l15;
            int ago = (quad ^ ((an >> 1) & 3)) << 3;
            ah[t] = *(const short8*)&sAh[an * 32 + ago];
            al[t] = *(const short8*)&sAl[an * 32 + ago];
            int brow = wj * 64 + t * 16 + l15;
            bh[t] = *(const short8*)&sBh[brow * 32 + quad * 8];
            bl[t] = *(const short8*)&sBl[brow * 32 + quad * 8];
        }
#pragma unroll
        for (int nt = 0; nt < 4; nt++)
#pragma unroll
            for (int jt = 0; jt < 4; jt++) {
                acc[nt][jt] = __builtin_amdgcn_mfma_f32_16x16x32_bf16(ah[nt], bh[jt], acc[nt][jt], 0, 0, 0);
                acc[nt][jt] = __builtin_amdgcn_mfma_f32_16x16x32_bf16(ah[nt], bl[jt], acc[nt][jt], 0, 0, 0);
                acc[nt][jt] = __builtin_amdgcn_mfma_f32_16x16x32_bf16(al[nt], bh[jt], acc[nt][jt], 0, 0, 0);
                acc[nt][jt] = __builtin_amdgcn_mfma_f32_16x16x32_bf16(al[nt], bl[jt], acc[nt][jt], 0, 0, 0);
            }
    }

#pragma unroll
    for (int jt = 0; jt < 4; jt++) {
        int j = wj * 64 + jt * 16 + l15;
        float bj = bias[j];
#pragma unroll
        for (int nt = 0; nt < 4; nt++) {
            int nb = n0 + wn * 64 + nt * 16 + quad * 4;
            f32x4 z = acc[nt][jt];
#pragma unroll
            for (int r = 0; r < 4; r++) z[r] += bj;
            if (LAYER == 1) {
#pragma unroll
                for (int r = 0; r < 4; r++) z[r] = 1.f / (1.f + __expf(-z[r]));
                if (j < 64) {
                    us4 h4, l4;
#pragma unroll
                    for (int r = 0; r < 4; r++) {
                        float x2 = z[r] * state[((size_t)b * NN + nb + r) * 64 + j];
                        ushort_t h, l; split_bf(x2, h, l);
                        h4[r] = h; l4[r] = l;
                    }
                    size_t o = pidx(b, 2 + j, nb);
                    *(us4*)&Xhw[o] = h4;
                    *(us4*)&Xlw[o] = l4;
                } else {
                    *(f32x4*)&U[((size_t)b * 64 + j - 64) * NN + nb] = z;
                }
            } else {
                f32x4 u4 = *(const f32x4*)&U[((size_t)b * 64 + j) * NN + nb];
#pragma unroll
                for (int r = 0; r < 4; r++) {
                    float c = tanhf(z[r]);
                    float s = state[((size_t)b * NN + nb + r) * 64 + j];
                    out[((size_t)b * NN + nb + r) * 64 + j] = u4[r] * s + (1.f - u4[r]) * c;
                }
            }
        }
    }
}

extern "C" void kernel_launch(void* const* d_in, const int* in_sizes, int n_in,
                              void* d_out, int out_size, void* d_ws, size_t ws_size,
                              hipStream_t stream) {
    const float* input = (const float*)d_in[0];
    const float* state = (const float*)d_in[1];
    const float* A0    = (const float*)d_in[2];
    const float* A1    = (const float*)d_in[3];
    const float* nv1_1 = (const float*)d_in[4];
    const float* nv2_1 = (const float*)d_in[5];
    const float* W1    = (const float*)d_in[6];
    const float* b1    = (const float*)d_in[7];
    const float* nv1_2 = (const float*)d_in[8];
    const float* nv2_2 = (const float*)d_in[9];
    const float* W2    = (const float*)d_in[10];
    const float* b2    = (const float*)d_in[11];
    float* out = (float*)d_out;

    char* p = (char*)d_ws;
    auto alloc = [&](size_t bytes) { void* r = (void*)p; p += (bytes + 255) & ~(size_t)255; return r; };
    float*    ADP1 = (float*)alloc(AN * 4);
    float*    ADP2 = (float*)alloc(AN * 4);
    ushort_t* Ahi  = (ushort_t*)alloc(4 * AN * 2);
    ushort_t* Alo  = (ushort_t*)alloc(4 * AN * 2);
    ushort_t* Xh   = (ushort_t*)alloc((size_t)BB * HB * NN * 2);
    ushort_t* Xl   = (ushort_t*)alloc((size_t)BB * HB * NN * 2);
    ushort_t* Wt1h = (ushort_t*)alloc((size_t)128 * KTOT * 2);
    ushort_t* Wt1l = (ushort_t*)alloc((size_t)128 * KTOT * 2);
    ushort_t* Wt2h = (ushort_t*)alloc((size_t)64 * KTOT * 2);
    ushort_t* Wt2l = (ushort_t*)alloc((size_t)64 * KTOT * 2);
    float*    U    = (float*)alloc((size_t)BB * 64 * NN * 4);

    adp_pair_kernel<<<dim3(NN, 1, 2), NN, 0, stream>>>(nv1_1, nv2_1, nv1_2, nv2_2, ADP1, ADP2);
    prep_misc_kernel<<<192 + BB * CIN * 64 / 256, 256, 0, stream>>>(W1, W2, input, state,
                                                                    Wt1h, Wt1l, Wt2h, Wt2l, Xh, Xl);
    asplit_kernel<<<dim3(16, 16, 4), 256, 0, stream>>>(A0, A1, ADP1, ADP2, Ahi, Alo);

    dim3 gf(QQ / 64, 1, 3);
    // layer 1: both diffusion hops in one dispatch
    diff_fused<<<gf, 512, 0, stream>>>(Ahi, Alo, Xh, Xl, 2);
    proj_mfma<128, 1, 128><<<dim3(NN / 128, BB), 256, 0, stream>>>(Xh, Xl, Wt1h, Wt1l, b1, state,
                                                                   U, Xh, Xl, nullptr);
    // layer 2 (Xpack frows 2..65 now hold r*state)
    diff_fused<<<gf, 512, 0, stream>>>(Ahi, Alo, Xh, Xl, 3);
    proj_mfma<64, 2, 256><<<dim3(NN / 256, BB), 256, 0, stream>>>(Xh, Xl, Wt2h, Wt2l, b2, state,
                                                                  U, nullptr, nullptr, out);
}

// Round 10
// 402.301 us; speedup vs baseline: 1.0906x; 1.0906x over previous
//
#include <hip/hip_runtime.h>
#include <math.h>

#define NN 512
#define BB 128
#define CIN 66
#define QQ (BB*CIN)            // 8448
#define AN ((size_t)NN*NN)
#define HB 480                 // feature rows per batch: 462 used (7 segs x 66)
#define KTOT 480               // padded K for proj (Wt rows 462..479 are zero)

typedef unsigned short ushort_t;
typedef __attribute__((ext_vector_type(8))) short short8;
typedef __attribute__((ext_vector_type(8))) unsigned short us8;
typedef __attribute__((ext_vector_type(4))) float f32x4;
typedef __attribute__((ext_vector_type(4))) unsigned short us4;

// Fragment-packed X layout ("Xpack"): element (b, frow, n) lives at
//   ((b*30 + frow/16) << 13) + ((n/8) << 7) + ((frow%16) << 3) + (n%8)
__device__ __forceinline__ size_t pidx(int b, int frow, int n) {
    return ((size_t)(b * 30 + (frow >> 4)) << 13) + ((size_t)(n >> 3) << 7)
         + ((frow & 15) << 3) + (n & 7);
}

__device__ __forceinline__ ushort_t f2bf(float f) {
    unsigned u = __float_as_uint(f);
    u += 0x7FFF + ((u >> 16) & 1);
    return (ushort_t)(u >> 16);
}
__device__ __forceinline__ float bf2f(ushort_t h) {
    return __uint_as_float(((unsigned)h) << 16);
}
__device__ __forceinline__ void split_bf(float f, ushort_t& hi, ushort_t& lo) {
    hi = f2bf(f);
    lo = f2bf(f - bf2f(hi));
}
__device__ __forceinline__ void gload_lds16(const void* g, void* l) {
    __builtin_amdgcn_global_load_lds(
        (const __attribute__((address_space(1))) unsigned*)g,
        (__attribute__((address_space(3))) unsigned*)l, 16, 0, 0);
}

// ---------- adp pair: z selects (nv1_1,nv2_1)->ADP1 or (nv1_2,nv2_2)->ADP2 ----------
__global__ __launch_bounds__(512) void adp_pair_kernel(const float* __restrict__ nv1a,
                                                       const float* __restrict__ nv2a,
                                                       const float* __restrict__ nv1b,
                                                       const float* __restrict__ nv2b,
                                                       float* __restrict__ adp1,
                                                       float* __restrict__ adp2) {
    const float* nv1 = blockIdx.z ? nv1b : nv1a;
    const float* nv2 = blockIdx.z ? nv2b : nv2a;
    float* adp       = blockIdx.z ? adp2 : adp1;
    int n = blockIdx.x;
    int m = threadIdx.x;
    float z = 0.f;
#pragma unroll
    for (int k = 0; k < 10; k++) z = fmaf(nv1[n * 10 + k], nv2[k * NN + m], z);
    z = fmaxf(z, 0.f);

    __shared__ float sred[8];
    int wid  = threadIdx.x >> 6;
    int lane = threadIdx.x & 63;

    float v = z;
#pragma unroll
    for (int off = 32; off; off >>= 1) v = fmaxf(v, __shfl_down(v, off, 64));
    if (lane == 0) sred[wid] = v;
    __syncthreads();
    float zmax = sred[0];
#pragma unroll
    for (int i = 1; i < 8; i++) zmax = fmaxf(zmax, sred[i]);

    float e = __expf(z - zmax);
    __syncthreads();
    v = e;
#pragma unroll
    for (int off = 32; off; off >>= 1) v += __shfl_down(v, off, 64);
    if (lane == 0) sred[wid] = v;
    __syncthreads();
    float tot = 0.f;
#pragma unroll
    for (int i = 0; i < 8; i++) tot += sred[i];

    adp[n * NN + m] = e / tot;
}

// ---------- transpose + bf16-split supports into MFMA-fragment-packed layout ----------
// Apack[s][kt][mt][lane][8]: lane = quad*16 + (m&15), elems k = kt*32 + quad*8 + j
__global__ __launch_bounds__(256) void asplit_kernel(const float* __restrict__ A0,
                                                     const float* __restrict__ A1,
                                                     const float* __restrict__ P1,
                                                     const float* __restrict__ P2,
                                                     ushort_t* __restrict__ Ahi,
                                                     ushort_t* __restrict__ Alo) {
    __shared__ float t[32][33];
    int s = blockIdx.z;
    const float* src = (s == 0) ? A0 : (s == 1) ? A1 : (s == 2) ? P1 : P2;
    int m0 = blockIdx.x * 32, k0 = blockIdx.y * 32;
    int tx = threadIdx.x & 31, ty = threadIdx.x >> 5;
#pragma unroll
    for (int r = 0; r < 32; r += 8)
        t[ty + r][tx] = src[(size_t)(k0 + ty + r) * NN + m0 + tx];
    __syncthreads();
#pragma unroll
    for (int r = 0; r < 32; r += 8) {
        int m = m0 + ty + r, k = k0 + tx;
        float v = t[tx][ty + r];   // = src[k][m]
        ushort_t h, l; split_bf(v, h, l);
        int mt = m >> 4, l15 = m & 15;
        int kt = k >> 5, quad = (k >> 3) & 3, j = k & 7;
        size_t o = ((((size_t)s * 16 + kt) * 32 + mt) * 64 + quad * 16 + l15) * 8 + j;
        Ahi[o] = h; Alo[o] = l;
    }
}

// ---------- fused misc prep: wtprep(W1) + wtprep(W2) + buildx, by block range ----------
__global__ __launch_bounds__(256) void prep_misc_kernel(const float* __restrict__ W1,
                                                        const float* __restrict__ W2,
                                                        const float* __restrict__ inp,
                                                        const float* __restrict__ st,
                                                        ushort_t* __restrict__ Wt1h,
                                                        ushort_t* __restrict__ Wt1l,
                                                        ushort_t* __restrict__ Wt2h,
                                                        ushort_t* __restrict__ Wt2l,
                                                        ushort_t* __restrict__ Xh,
                                                        ushort_t* __restrict__ Xl) {
    int blk = blockIdx.x;
    if (blk < 128) {                       // Wt1[j][KTOT]
        int j = blk;
        for (int k = threadIdx.x; k < KTOT; k += 256) {
            float v = (k < 462) ? W1[(size_t)k * 128 + j] : 0.f;
            ushort_t h, l; split_bf(v, h, l);
            Wt1h[(size_t)j * KTOT + k] = h;
            Wt1l[(size_t)j * KTOT + k] = l;
        }
    } else if (blk < 192) {                // Wt2[j][KTOT]
        int j = blk - 128;
        for (int k = threadIdx.x; k < KTOT; k += 256) {
            float v = (k < 462) ? W2[(size_t)k * 64 + j] : 0.f;
            ushort_t h, l; split_bf(v, h, l);
            Wt2h[(size_t)j * KTOT + k] = h;
            Wt2l[(size_t)j * KTOT + k] = l;
        }
    } else {                               // buildx: Xpack frows 0..65
        int gid = (blk - 192) * 256 + threadIdx.x;   // over 128*66*64
        int ch  = gid & 63;
        int c   = (gid >> 6) % CIN;
        int b   = gid / (64 * CIN);
        int n0  = ch * 8;
        us8 h8, l8;
#pragma unroll
        for (int r = 0; r < 8; r++) {
            int n = n0 + r;
            float v = (c < 2) ? inp[((size_t)b * NN + n) * 2 + c]
                              : st[((size_t)b * NN + n) * 64 + (c - 2)];
            ushort_t h, l; split_bf(v, h, l);
            h8[r] = h; l8[r] = l;
        }
        size_t o = pidx(b, c, n0);
        *(us8*)&Xh[o] = h8;
        *(us8*)&Xl[o] = l8;
    }
}

// ---------- fused 2-hop diffusion GEMM (R7 structure, 3-term split) ----------
// Block owns a 32-wide q-slab and ALL 512 nodes. 8 waves of 64m x 32q.
// Phase 1: x1 = A^T x from global fragment-packed operands; x1 -> global Xpack
// (frow 66+132s) AND full hi+lo park in LDS. One barrier. Phase 2: x2 = A^T x1
// with x1 frags served entirely from LDS; writes frow 132+132s.
__global__ __launch_bounds__(512, 4) void diff_fused(const ushort_t* __restrict__ Aph,
                                                     const ushort_t* __restrict__ Apl,
                                                     ushort_t* Xh, ushort_t* Xl, int s2) {
    __shared__ ushort_t sX1h[32 * 520];   // [qloc][n], row stride 520 (bank-stagger)
    __shared__ ushort_t sX1l[32 * 520];
    const int tid  = threadIdx.x;
    const int lane = tid & 63, w = tid >> 6;          // w 0..7
    const int quad = lane >> 4, l15 = lane & 15;
    const int q0 = blockIdx.x * 32;
    const int sz = blockIdx.z;
    const int sup = (sz < 2) ? sz : s2;
    const size_t abase = (size_t)sup * 262144;        // 16*32*64*8
    const int mtg0 = w * 4;                           // wave m-base = w*64

    // X-frag base pointers for phase 1 (frows 0..65)
    const ushort_t* xph[2];
    const ushort_t* xpl[2];
    int bq[2], cq[2];
#pragma unroll
    for (int qt = 0; qt < 2; qt++) {
        int q = q0 + qt * 16 + l15;
        int b = q / 66, c = q - 66 * b;
        bq[qt] = b; cq[qt] = c;
        size_t off = ((size_t)(b * 30 + (c >> 4)) << 13) + ((c & 15) << 3)
                   + (size_t)quad * 128;
        xph[qt] = Xh + off;
        xpl[qt] = Xl + off;
    }

// 3-term split-bf16 product (lo*lo dropped — R3-validated numerics)
#define DMFMA2(ACC, AH, AL, XH, XL)                                                                \
    {                                                                                              \
        _Pragma("unroll")                                                                          \
        for (int mt = 0; mt < 4; mt++) {                                                           \
            _Pragma("unroll")                                                                      \
            for (int qt = 0; qt < 2; qt++) {                                                       \
                ACC[mt][qt] = __builtin_amdgcn_mfma_f32_16x16x32_bf16(AH[mt], XH[qt], ACC[mt][qt], 0, 0, 0); \
                ACC[mt][qt] = __builtin_amdgcn_mfma_f32_16x16x32_bf16(AH[mt], XL[qt], ACC[mt][qt], 0, 0, 0); \
                ACC[mt][qt] = __builtin_amdgcn_mfma_f32_16x16x32_bf16(AL[mt], XH[qt], ACC[mt][qt], 0, 0, 0); \
            }                                                                                      \
        }                                                                                          \
    }

    // ---------------- phase 1: x1 = A^T x ----------------
    {
        f32x4 acc[4][2] = {};
        for (int kt = 0; kt < 16; kt++) {
            short8 ah[4], al[4], xh2[2], xl2[2];
#pragma unroll
            for (int t = 0; t < 4; t++) {
                size_t fo = abase + ((size_t)kt * 32 + mtg0 + t) * 512 + lane * 8;
                ah[t] = *(const short8*)&Aph[fo];
                al[t] = *(const short8*)&Apl[fo];
            }
#pragma unroll
            for (int qt = 0; qt < 2; qt++) {
                xh2[qt] = *(const short8*)&xph[qt][(size_t)kt * 512];
                xl2[qt] = *(const short8*)&xpl[qt][(size_t)kt * 512];
            }
            DMFMA2(acc, ah, al, xh2, xl2);
        }
        // epilogue 1: x1 -> LDS + global
        const int rowo = 66 + 132 * sz;
#pragma unroll
        for (int qt = 0; qt < 2; qt++) {
            int qloc = qt * 16 + l15;
            int frow = rowo + cq[qt];
#pragma unroll
            for (int mt = 0; mt < 4; mt++) {
                int n = w * 64 + mt * 16 + quad * 4;
                us4 h4, l4;
#pragma unroll
                for (int r = 0; r < 4; r++) {
                    ushort_t h, l; split_bf(acc[mt][qt][r], h, l);
                    h4[r] = h; l4[r] = l;
                }
                *(us4*)&sX1h[qloc * 520 + n] = h4;
                *(us4*)&sX1l[qloc * 520 + n] = l4;
                size_t o = pidx(bq[qt], frow, n);
                *(us4*)&Xh[o] = h4;
                *(us4*)&Xl[o] = l4;
            }
        }
    }
    __syncthreads();

    // ---------------- phase 2: x2 = A^T x1 (x1 from LDS) ----------------
    {
        f32x4 acc[4][2] = {};
        for (int kt = 0; kt < 16; kt++) {
            short8 ah[4], al[4], bh2[2], bl2[2];
#pragma unroll
            for (int t = 0; t < 4; t++) {
                size_t fo = abase + ((size_t)kt * 32 + mtg0 + t) * 512 + lane * 8;
                ah[t] = *(const short8*)&Aph[fo];
                al[t] = *(const short8*)&Apl[fo];
            }
#pragma unroll
            for (int qt = 0; qt < 2; qt++) {
                int idx = (qt * 16 + l15) * 520 + kt * 32 + quad * 8;
                bh2[qt] = *(const short8*)&sX1h[idx];
                bl2[qt] = *(const short8*)&sX1l[idx];
            }
            DMFMA2(acc, ah, al, bh2, bl2);
        }
        // epilogue 2: x2 -> global
        const int rowo = 132 + 132 * sz;
#pragma unroll
        for (int qt = 0; qt < 2; qt++) {
            int frow = rowo + cq[qt];
#pragma unroll
            for (int mt = 0; mt < 4; mt++) {
                int n = w * 64 + mt * 16 + quad * 4;
                us4 h4, l4;
#pragma unroll
                for (int r = 0; r < 4; r++) {
                    ushort_t h, l; split_bf(acc[mt][qt][r], h, l);
                    h4[r] = h; l4[r] = l;
                }
                size_t o = pidx(bq[qt], frow, n);
                *(us4*)&Xh[o] = h4;
                *(us4*)&Xl[o] = l4;
            }
        }
    }
#undef DMFMA2
}

// ---------- projection GEMM (MFMA, 3-term split), A transposed in LDS from Xpack ----------
// out[n][j] = sum_f Xpack[b][f][n] * Wt[j][f]   (f = 480, 15 steps of 32)
// LAYER1 (COUT=128, BM=128): sigmoid; j<64 -> r*state into Xpack frows 2+j; j>=64 -> U
// LAYER2 (COUT=64, BM=256): tanh + gate -> out
template <int COUT, int LAYER, int BM>
__global__ __launch_bounds__(256) void proj_mfma(const ushort_t* XhC, const ushort_t* XlC,
                                                 const ushort_t* __restrict__ Wth,
                                                 const ushort_t* __restrict__ Wtl,
                                                 const float* __restrict__ bias,
                                                 const float* __restrict__ state,
                                                 float* U,
                                                 ushort_t* Xhw, ushort_t* Xlw,
                                                 float* __restrict__ out) {
    __shared__ ushort_t sAh[BM * 32];
    __shared__ ushort_t sAl[BM * 32];
    __shared__ ushort_t sBh[COUT * 32];
    __shared__ ushort_t sBl[COUT * 32];
    constexpr int PB = COUT / 64;
    const int tid  = threadIdx.x;
    const int lane = tid & 63, w = tid >> 6;
    const int quad = lane >> 4, l15 = lane & 15;
    const int b = blockIdx.y, n0 = blockIdx.x * BM;
    const int wn = (COUT == 128) ? (w & 1) : w;
    const int wj = (COUT == 128) ? (w >> 1) : 0;
    const int kp = tid & 15, n8 = tid >> 4;

    size_t boff[PB]; int lB[PB];
#pragma unroll
    for (int p = 0; p < PB; p++) {
        int cid = p * 256 + tid;
        lB[p]   = cid * 8;
        boff[p] = (size_t)(cid >> 2) * KTOT + (cid & 3) * 8;
    }

    f32x4 acc[4][4] = {};

    for (int k0 = 0; k0 < KTOT; k0 += 32) {
        __syncthreads();
        // ---- A: load Xpack (f-pairs at 8 consecutive n), write transposed into sAt[n][f] ----
#pragma unroll
        for (int pass = 0; pass < BM / 128; pass++) {
            int np0 = (n8 + pass * 16) * 8;
            int kk  = k0 + 2 * kp;                 // kk&15 even -> kk,kk+1 in same tile
            size_t o = pidx(b, kk, n0 + np0);
            us8 h0 = *(const us8*)&XhC[o];
            us8 h1 = *(const us8*)&XhC[o + 8];
            us8 l0 = *(const us8*)&XlC[o];
            us8 l1 = *(const us8*)&XlC[o + 8];
            int g = kp >> 2, ko = (2 * kp) & 7;
#pragma unroll
            for (int j2 = 0; j2 < 8; j2++) {
                int n   = np0 + j2;
                int idx = n * 32 + ((g ^ ((n >> 1) & 3)) << 3) + ko;
                *(unsigned*)&sAh[idx] = (unsigned)h0[j2] | ((unsigned)h1[j2] << 16);
                *(unsigned*)&sAl[idx] = (unsigned)l0[j2] | ((unsigned)l1[j2] << 16);
            }
        }
        // ---- B: k-contiguous async staging ----
#pragma unroll
        for (int p = 0; p < PB; p++) {
            gload_lds16(Wth + boff[p] + k0, sBh + lB[p]);
            gload_lds16(Wtl + boff[p] + k0, sBl + lB[p]);
        }
        __syncthreads();
        short8 ah[4], al[4], bh[4], bl[4];
#pragma unroll
        for (int t = 0; t < 4; t++) {
            int an  = wn * 64 + t * 16 + l15;
            int ago = (quad ^ ((an >> 1) & 3)) << 3;
            ah[t] = *(const short8*)&sAh[an * 32 + ago];
            al[t] = *(const short8*)&sAl[an * 32 + ago];
            int brow = wj * 64 + t * 16 + l15;
            bh[t] = *(const short8*)&sBh[brow * 32 + quad * 8];
            bl[t] = *(const short8*)&sBl[brow * 32 + quad * 8];
        }
#pragma unroll
        for (int nt = 0; nt < 4; nt++)
#pragma unroll
            for (int jt = 0; jt < 4; jt++) {
                acc[nt][jt] = __builtin_amdgcn_mfma_f32_16x16x32_bf16(ah[nt], bh[jt], acc[nt][jt], 0, 0, 0);
                acc[nt][jt] = __builtin_amdgcn_mfma_f32_16x16x32_bf16(ah[nt], bl[jt], acc[nt][jt], 0, 0, 0);
                acc[nt][jt] = __builtin_amdgcn_mfma_f32_16x16x32_bf16(al[nt], bh[jt], acc[nt][jt], 0, 0, 0);
            }
    }

#pragma unroll
    for (int jt = 0; jt < 4; jt++) {
        int j = wj * 64 + jt * 16 + l15;
        float bj = bias[j];
#pragma unroll
        for (int nt = 0; nt < 4; nt++) {
            int nb = n0 + wn * 64 + nt * 16 + quad * 4;
            f32x4 z = acc[nt][jt];
#pragma unroll
            for (int r = 0; r < 4; r++) z[r] += bj;
            if (LAYER == 1) {
#pragma unroll
                for (int r = 0; r < 4; r++) z[r] = 1.f / (1.f + __expf(-z[r]));
                if (j < 64) {
                    us4 h4, l4;
#pragma unroll
                    for (int r = 0; r < 4; r++) {
                        float x2 = z[r] * state[((size_t)b * NN + nb + r) * 64 + j];
                        ushort_t h, l; split_bf(x2, h, l);
                        h4[r] = h; l4[r] = l;
                    }
                    size_t o = pidx(b, 2 + j, nb);
                    *(us4*)&Xhw[o] = h4;
                    *(us4*)&Xlw[o] = l4;
                } else {
                    *(f32x4*)&U[((size_t)b * 64 + j - 64) * NN + nb] = z;
                }
            } else {
                f32x4 u4 = *(const f32x4*)&U[((size_t)b * 64 + j) * NN + nb];
#pragma unroll
                for (int r = 0; r < 4; r++) {
                    float c = tanhf(z[r]);
                    float s = state[((size_t)b * NN + nb + r) * 64 + j];
                    out[((size_t)b * NN + nb + r) * 64 + j] = u4[r] * s + (1.f - u4[r]) * c;
                }
            }
        }
    }
}

extern "C" void kernel_launch(void* const* d_in, const int* in_sizes, int n_in,
                              void* d_out, int out_size, void* d_ws, size_t ws_size,
                              hipStream_t stream) {
    const float* input = (const float*)d_in[0];
    const float* state = (const float*)d_in[1];
    const float* A0    = (const float*)d_in[2];
    const float* A1    = (const float*)d_in[3];
    const float* nv1_1 = (const float*)d_in[4];
    const float* nv2_1 = (const float*)d_in[5];
    const float* W1    = (const float*)d_in[6];
    const float* b1    = (const float*)d_in[7];
    const float* nv1_2 = (const float*)d_in[8];
    const float* nv2_2 = (const float*)d_in[9];
    const float* W2    = (const float*)d_in[10];
    const float* b2    = (const float*)d_in[11];
    float* out = (float*)d_out;

    char* p = (char*)d_ws;
    auto alloc = [&](size_t bytes) { void* r = (void*)p; p += (bytes + 255) & ~(size_t)255; return r; };
    float*    ADP1 = (float*)alloc(AN * 4);
    float*    ADP2 = (float*)alloc(AN * 4);
    ushort_t* Ahi  = (ushort_t*)alloc(4 * AN * 2);
    ushort_t* Alo  = (ushort_t*)alloc(4 * AN * 2);
    ushort_t* Xh   = (ushort_t*)alloc((size_t)BB * HB * NN * 2);
    ushort_t* Xl   = (ushort_t*)alloc((size_t)BB * HB * NN * 2);
    ushort_t* Wt1h = (ushort_t*)alloc((size_t)128 * KTOT * 2);
    ushort_t* Wt1l = (ushort_t*)alloc((size_t)128 * KTOT * 2);
    ushort_t* Wt2h = (ushort_t*)alloc((size_t)64 * KTOT * 2);
    ushort_t* Wt2l = (ushort_t*)alloc((size_t)64 * KTOT * 2);
    float*    U    = (float*)alloc((size_t)BB * 64 * NN * 4);

    prep_misc_kernel<<<192 + BB * CIN * 64 / 256, 256, 0, stream>>>(W1, W2, input, state,
                                                                    Wt1h, Wt1l, Wt2h, Wt2l, Xh, Xl);
    adp_pair_kernel<<<dim3(NN, 1, 2), NN, 0, stream>>>(nv1_1, nv2_1, nv1_2, nv2_2, ADP1, ADP2);
    asplit_kernel<<<dim3(16, 16, 4), 256, 0, stream>>>(A0, A1, ADP1, ADP2, Ahi, Alo);

    dim3 gf(QQ / 32, 1, 3);
    // layer 1: both diffusion hops in one dispatch
    diff_fused<<<gf, 512, 0, stream>>>(Ahi, Alo, Xh, Xl, 2);
    proj_mfma<128, 1, 128><<<dim3(NN / 128, BB), 256, 0, stream>>>(Xh, Xl, Wt1h, Wt1l, b1, state,
                                                                   U, Xh, Xl, nullptr);
    // layer 2 (Xpack frows 2..65 now hold r*state)
    diff_fused<<<gf, 512, 0, stream>>>(Ahi, Alo, Xh, Xl, 3);
    proj_mfma<64, 2, 256><<<dim3(NN / 256, BB), 256, 0, stream>>>(Xh, Xl, Wt2h, Wt2l, b2, state,
                                                                  U, nullptr, nullptr, out);
}